// Round 5
// baseline (99.325 us; speedup 1.0000x reference)
//
#include <hip/hip_runtime.h>

#define N 8192
#define DIM 64

typedef float f32x4 __attribute__((ext_vector_type(4)));
typedef short bf16x8 __attribute__((ext_vector_type(8)));
typedef unsigned short u16;

__device__ __forceinline__ u16 f32_to_bf16_rne(float f) {
  unsigned int u = __float_as_uint(f);
  return (u16)((u + 0x7FFFu + ((u >> 16) & 1u)) >> 16);
}

// x [8192][64] f32 -> xbT [64][8192] bf16 via LDS transpose. 128 blocks x 256 thr.
__global__ void cvtT_kernel(const float* __restrict__ x, u16* __restrict__ xbT) {
  __shared__ float st[64][68];
  int t = threadIdx.x;
  int i0 = blockIdx.x * 64;
  int r = t >> 2, cq = t & 3;
#pragma unroll
  for (int m = 0; m < 4; ++m) {
    f32x4 v = *reinterpret_cast<const f32x4*>(x + (size_t)(i0 + r) * DIM + cq * 16 + m * 4);
    *reinterpret_cast<f32x4*>(&st[r][cq * 16 + m * 4]) = v;
  }
  __syncthreads();
  int d = t >> 2, iq = t & 3;
  alignas(16) u16 vb[16];
#pragma unroll
  for (int m = 0; m < 16; ++m) vb[m] = f32_to_bf16_rne(st[iq * 16 + m][d]);
  u16* dst = xbT + (size_t)d * N + i0 + iq * 16;
  *reinterpret_cast<bf16x8*>(dst) = *reinterpret_cast<bf16x8*>(&vb[0]);
  *reinterpret_cast<bf16x8*>(dst + 8) = *reinterpret_cast<bf16x8*>(&vb[8]);
}

// Ax partials. 2048 blocks = 512 i-tiles x 4 k-slices; 256 thr = 4 waves.
// Wave w: rows [i0, i0+16), k in [kb*2048 + w*512, +512) as 16 chunks of 32.
// Per-wave independent: A staged f32 via global_load_lds into a private 2-buf
// LDS ring (zero VGPR cost), counted vmcnt(2), NO barriers in the loop.
// 8 blocks/CU (32 waves/CU) via <=64 VGPR.
__global__ __launch_bounds__(256, 8) void ax_kernel(const float* __restrict__ A,
                                                    const u16* __restrict__ xbT,
                                                    float* __restrict__ spart) {
  __shared__ float ring[4][2][16][32];  // 16 KiB: [wave][buf][row][k]
  int bid = blockIdx.x;
  int i0 = (bid >> 2) * 16;
  int kb = bid & 3;
  int tid = threadIdx.x;
  int w = tid >> 6, lane = tid & 63;
  int c = lane & 15, q = lane >> 4;
  int kwbase = kb * 2048 + w * 512;

  // A source: inst e covers rows e*8+(lane>>3), 128B per row; chunk s adds s*32 floats.
  const float* Abase = A + (size_t)(i0 + (lane >> 3)) * N + kwbase + (lane & 7) * 4;
  // B source: lane (c,q) reads xbT[nt*16+c][k0g + q*8], 16B.
  const u16* Bbase = xbT + (size_t)c * N + kwbase + q * 8;

  f32x4 acc[4];
#pragma unroll
  for (int nt = 0; nt < 4; ++nt) acc[nt] = (f32x4){0.f, 0.f, 0.f, 0.f};

#define STAGE(s_)                                                               \
  {                                                                             \
    _Pragma("unroll") for (int e = 0; e < 2; ++e) {                             \
      const float* gp_ = Abase + (size_t)(e * 8) * N + (s_)*32;                 \
      __builtin_amdgcn_global_load_lds(                                         \
          (const __attribute__((address_space(1))) unsigned int*)gp_,           \
          (__attribute__((address_space(3))) unsigned int*)&ring[w][(s_)&1][e * 8][0], \
          16, 0, 0);                                                            \
    }                                                                           \
  }

  STAGE(0);

#pragma unroll
  for (int s = 0; s < 16; ++s) {
    if (s < 15) {
      STAGE(s + 1);
      asm volatile("s_waitcnt vmcnt(2)" ::: "memory");  // stage s landed
    } else {
      asm volatile("s_waitcnt vmcnt(0)" ::: "memory");
    }
    __builtin_amdgcn_sched_barrier(0);

    // A-frag: row c, k = s*32 + q*8 .. +8 (f32 -> bf16)
    const float* ap = &ring[w][s & 1][c][q * 8];
    f32x4 lo = *reinterpret_cast<const f32x4*>(ap);
    f32x4 hi = *reinterpret_cast<const f32x4*>(ap + 4);
    bf16x8 afv;
    afv[0] = (short)f32_to_bf16_rne(lo[0]);
    afv[1] = (short)f32_to_bf16_rne(lo[1]);
    afv[2] = (short)f32_to_bf16_rne(lo[2]);
    afv[3] = (short)f32_to_bf16_rne(lo[3]);
    afv[4] = (short)f32_to_bf16_rne(hi[0]);
    afv[5] = (short)f32_to_bf16_rne(hi[1]);
    afv[6] = (short)f32_to_bf16_rne(hi[2]);
    afv[7] = (short)f32_to_bf16_rne(hi[3]);

    // B-frags issued AFTER the stage wait -> compiler's B-wait keeps stage s+1 in flight
    const u16* bp = Bbase + s * 32;
#pragma unroll
    for (int nt = 0; nt < 4; ++nt) {
      bf16x8 bfv = *reinterpret_cast<const bf16x8*>(bp + (size_t)(nt * 16) * N);
      acc[nt] = __builtin_amdgcn_mfma_f32_16x16x32_bf16(afv, bfv, acc[nt], 0, 0, 0);
    }
  }
#undef STAGE

  // Reduce the 4 waves' K-partials. acc[nt][v] = partial Ax[i0+q*4+v][nt*16+c].
  __syncthreads();  // all waves done with their rings
  float* red = (float*)ring;  // [w][16 rows][64 d] f32 = 16 KiB
#pragma unroll
  for (int nt = 0; nt < 4; ++nt)
#pragma unroll
    for (int v = 0; v < 4; ++v)
      red[(w * 16 + q * 4 + v) * 64 + nt * 16 + c] = acc[nt][v];
  __syncthreads();
  int ii = tid >> 4, dq = tid & 15;
  f32x4 sum = *reinterpret_cast<f32x4*>(&red[(0 * 16 + ii) * 64 + dq * 4]);
#pragma unroll
  for (int ww = 1; ww < 4; ++ww)
    sum += *reinterpret_cast<f32x4*>(&red[(ww * 16 + ii) * 64 + dq * 4]);
  *reinterpret_cast<f32x4*>(&spart[((size_t)kb * N + i0 + ii) * 64 + dq * 4]) = sum;
}

// out[i][d] = 1 - 0.1*x[i][d] - 0.01*<x_i, Ax_i>, Ax = sum of 4 k-slice partials.
__global__ void finish_kernel(const float* __restrict__ x,
                              const float* __restrict__ spart,
                              float* __restrict__ out) {
  int tid = threadIdx.x;
  int i = blockIdx.x * 16 + (tid >> 4);
  int dq = tid & 15;
  size_t base = (size_t)i * DIM + dq * 4;
  f32x4 xv = *reinterpret_cast<const f32x4*>(x + base);
  f32x4 av = *reinterpret_cast<const f32x4*>(spart + base);
#pragma unroll
  for (int kb = 1; kb < 4; ++kb)
    av += *reinterpret_cast<const f32x4*>(spart + (size_t)kb * N * DIM + base);
  float p = xv[0] * av[0] + xv[1] * av[1] + xv[2] * av[2] + xv[3] * av[3];
  p += __shfl_xor(p, 1);
  p += __shfl_xor(p, 2);
  p += __shfl_xor(p, 4);
  p += __shfl_xor(p, 8);
  f32x4 o;
  o[0] = 1.0f - 0.1f * xv[0] - 0.01f * p;
  o[1] = 1.0f - 0.1f * xv[1] - 0.01f * p;
  o[2] = 1.0f - 0.1f * xv[2] - 0.01f * p;
  o[3] = 1.0f - 0.1f * xv[3] - 0.01f * p;
  *reinterpret_cast<f32x4*>(out + base) = o;
}

extern "C" void kernel_launch(void* const* d_in, const int* in_sizes, int n_in,
                              void* d_out, int out_size, void* d_ws, size_t ws_size,
                              hipStream_t stream) {
  // d_in[0] = t (unused), d_in[1] = x f32 [8192][64], d_in[2] = A f32 [8192][8192]
  const float* x = (const float*)d_in[1];
  const float* A = (const float*)d_in[2];
  float* out = (float*)d_out;

  u16* xbT = (u16*)d_ws;                                           // 1 MiB bf16 x^T
  float* spart = (float*)((char*)d_ws + (size_t)2 * 1024 * 1024);  // 8 MiB: [4][8192][64]

  cvtT_kernel<<<128, 256, 0, stream>>>(x, xbT);
  ax_kernel<<<2048, 256, 0, stream>>>(A, xbT, spart);
  finish_kernel<<<512, 256, 0, stream>>>(x, spart, out);
}

// Round 6
// 84.204 us; speedup vs baseline: 1.1796x; 1.1796x over previous
//
#include <hip/hip_runtime.h>

#define N 8192
#define DIM 64

typedef float f32x4 __attribute__((ext_vector_type(4)));
typedef short bf16x8 __attribute__((ext_vector_type(8)));

__device__ __forceinline__ unsigned short f32_to_bf16_rne(float f) {
  unsigned int u = __float_as_uint(f);
  unsigned int r = (u + 0x7FFFu + ((u >> 16) & 1u)) >> 16;
  return (unsigned short)r;
}

// x (f32 [N][64]) -> xb (bf16 [N][64]); 131072 threads, 4 elems each
__global__ void cvt_kernel(const float* __restrict__ x, unsigned short* __restrict__ xb) {
  int gid = blockIdx.x * blockDim.x + threadIdx.x;
  float4 v = reinterpret_cast<const float4*>(x)[gid];
  ushort4 o;
  o.x = f32_to_bf16_rne(v.x);
  o.y = f32_to_bf16_rne(v.y);
  o.z = f32_to_bf16_rne(v.z);
  o.w = f32_to_bf16_rne(v.w);
  reinterpret_cast<ushort4*>(xb)[gid] = o;
}

// Grid: 1024 blocks = 128 row-groups x 8 j-chunks, 256 threads (4 waves).
// Wave w of block (rg, js): rows i0..i0+63, j in [js*1024 + w*256, +256).
// Swapped-Gram: D[j'][i'] = mfma(xj_frag, xi_frag); lane (q,c) holds
// G[jt*16+q*4+v][i0+it*16+c] -> A loads are contiguous float4 along j.
// A loads are NON-TEMPORAL (nt): A is read exactly once -> skip L2 allocation.
__global__ __launch_bounds__(256, 4) void main_kernel(
    const float* __restrict__ A,
    const unsigned short* __restrict__ xb,
    float* __restrict__ spart) {
  int bid = blockIdx.x;
  int rg = bid & 127;
  int js = bid >> 7;
  int tid = threadIdx.x;
  int w = tid >> 6;
  int lane = tid & 63;
  int i0 = rg * 64;
  int jbase = js * 1024 + w * 256;
  int c = lane & 15;   // operand row/col selector, D column (i)
  int q = lane >> 4;   // k-quad; D row group (j)

  // B-operand fragments (i-side), persistent: B[k][col=c] = X[i0+it*16+c][k]
  bf16x8 xi[4][2];
#pragma unroll
  for (int it = 0; it < 4; ++it)
#pragma unroll
    for (int kb = 0; kb < 2; ++kb)
      xi[it][kb] = *reinterpret_cast<const bf16x8*>(
          xb + (size_t)(i0 + it * 16 + c) * DIM + kb * 32 + q * 8);

  // Per-it A row pointer: row i0+it*16+c, col jbase + q*4 (+ jt*16 folds to imm)
  const float* pA[4];
#pragma unroll
  for (int it = 0; it < 4; ++it)
    pA[it] = A + (size_t)(i0 + it * 16 + c) * N + jbase + q * 4;

  float sacc[4] = {0.f, 0.f, 0.f, 0.f};

  f32x4 a_buf[2][4];
  bf16x8 xj_buf[2][2];

  // prologue: jt=0 loads
#pragma unroll
  for (int it = 0; it < 4; ++it)
    a_buf[0][it] =
        __builtin_nontemporal_load(reinterpret_cast<const f32x4*>(pA[it]));
  {
    const unsigned short* pj = xb + (size_t)(jbase + c) * DIM + q * 8;
    xj_buf[0][0] = *reinterpret_cast<const bf16x8*>(pj);
    xj_buf[0][1] = *reinterpret_cast<const bf16x8*>(pj + 32);
  }

#pragma unroll
  for (int jt = 0; jt < 16; ++jt) {
    const int cur = jt & 1, nxt = cur ^ 1;
    if (jt < 15) {
#pragma unroll
      for (int it = 0; it < 4; ++it)
        a_buf[nxt][it] = __builtin_nontemporal_load(
            reinterpret_cast<const f32x4*>(pA[it] + (jt + 1) * 16));
      const unsigned short* pj =
          xb + (size_t)(jbase + (jt + 1) * 16 + c) * DIM + q * 8;
      xj_buf[nxt][0] = *reinterpret_cast<const bf16x8*>(pj);
      xj_buf[nxt][1] = *reinterpret_cast<const bf16x8*>(pj + 32);
    }
#pragma unroll
    for (int it = 0; it < 4; ++it) {
      f32x4 g = {0.f, 0.f, 0.f, 0.f};
      g = __builtin_amdgcn_mfma_f32_16x16x32_bf16(xj_buf[cur][0], xi[it][0], g, 0, 0, 0);
      g = __builtin_amdgcn_mfma_f32_16x16x32_bf16(xj_buf[cur][1], xi[it][1], g, 0, 0, 0);
      f32x4 a4 = a_buf[cur][it];
      sacc[it] = fmaf(a4[0], g[0], sacc[it]);
      sacc[it] = fmaf(a4[1], g[1], sacc[it]);
      sacc[it] = fmaf(a4[2], g[2], sacc[it]);
      sacc[it] = fmaf(a4[3], g[3], sacc[it]);
    }
  }

  // Sum over q (j sub-blocks within the wave): lanes c, c+16, c+32, c+48
#pragma unroll
  for (int it = 0; it < 4; ++it) {
    float s = sacc[it];
    s += __shfl_xor(s, 16);
    s += __shfl_xor(s, 32);
    sacc[it] = s;
  }

  __shared__ float red[4][64];
  if (q == 0) {
#pragma unroll
    for (int it = 0; it < 4; ++it)
      red[w][it * 16 + c] = sacc[it];
  }
  __syncthreads();
  if (tid < 64) {
    float s = red[0][tid] + red[1][tid] + red[2][tid] + red[3][tid];
    spart[(size_t)js * N + i0 + tid] = s;
  }
}

// out[i][d] = 1 - 0.1*x[i][d] - 0.01*sum_c spart[c][i]; 131072 threads, 4 elems each
__global__ void finish_kernel(const float* __restrict__ x,
                              const float* __restrict__ spart,
                              float* __restrict__ out) {
  int gid = blockIdx.x * blockDim.x + threadIdx.x;
  float4 xv = reinterpret_cast<const float4*>(x)[gid];
  int i = gid >> 4;  // (gid*4)/64
  float s = 0.f;
#pragma unroll
  for (int cc = 0; cc < 8; ++cc) s += spart[(size_t)cc * N + i];
  float4 o;
  o.x = 1.0f - 0.1f * xv.x - 0.01f * s;
  o.y = 1.0f - 0.1f * xv.y - 0.01f * s;
  o.z = 1.0f - 0.1f * xv.z - 0.01f * s;
  o.w = 1.0f - 0.1f * xv.w - 0.01f * s;
  reinterpret_cast<float4*>(out)[gid] = o;
}

extern "C" void kernel_launch(void* const* d_in, const int* in_sizes, int n_in,
                              void* d_out, int out_size, void* d_ws, size_t ws_size,
                              hipStream_t stream) {
  // d_in[0] = t (unused), d_in[1] = x f32 [8192][64], d_in[2] = A f32 [8192][8192]
  const float* x = (const float*)d_in[1];
  const float* A = (const float*)d_in[2];
  float* out = (float*)d_out;

  unsigned short* xb = (unsigned short*)d_ws;                  // 1 MB bf16 x
  float* spart = (float*)((char*)d_ws + (size_t)N * DIM * 2);  // 256 KB partials

  cvt_kernel<<<512, 256, 0, stream>>>(x, xb);
  main_kernel<<<1024, 256, 0, stream>>>(A, xb, spart);
  finish_kernel<<<512, 256, 0, stream>>>(x, spart, out);
}

// Round 7
// 74.277 us; speedup vs baseline: 1.3372x; 1.1336x over previous
//
#include <hip/hip_runtime.h>

#define N 8192
#define DIM 64

typedef float f32x4 __attribute__((ext_vector_type(4)));
typedef short bf16x8 __attribute__((ext_vector_type(8)));

__device__ __forceinline__ unsigned short f32_to_bf16_rne(float f) {
  unsigned int u = __float_as_uint(f);
  unsigned int r = (u + 0x7FFFu + ((u >> 16) & 1u)) >> 16;
  return (unsigned short)r;
}

// x (f32 [N][64]) -> xb (bf16 [N][64]); 131072 threads, 4 elems each
__global__ void cvt_kernel(const float* __restrict__ x, unsigned short* __restrict__ xb) {
  int gid = blockIdx.x * blockDim.x + threadIdx.x;
  float4 v = reinterpret_cast<const float4*>(x)[gid];
  ushort4 o;
  o.x = f32_to_bf16_rne(v.x);
  o.y = f32_to_bf16_rne(v.y);
  o.z = f32_to_bf16_rne(v.z);
  o.w = f32_to_bf16_rne(v.w);
  reinterpret_cast<ushort4*>(xb)[gid] = o;
}

// Grid: 1024 blocks = 128 row-groups x 8 j-chunks, 256 threads (4 waves).
// XCD-aware swizzle (T1): XCD x (= bid%8) owns contiguous A row-stripe
// [x*1024, (x+1)*1024) -> each XCD's L2/fabric path streams one 32MB stripe.
// Wave w of block (rg, js): rows i0..i0+63, j in [js*1024 + w*256, +256).
// Swapped-Gram: D[j'][i'] = mfma(xj_frag, xi_frag); lane (q,c) holds
// G[jt*16+q*4+v][i0+it*16+c] -> A loads are contiguous float4 along j.
__global__ __launch_bounds__(256, 4) void main_kernel(
    const float* __restrict__ A,
    const unsigned short* __restrict__ xb,
    float* __restrict__ spart) {
  int bid = blockIdx.x;
  int xcd = bid & 7;
  int slot = bid >> 3;               // 0..127 within XCD
  int rg = xcd * 16 + (slot & 15);   // contiguous 16 row-groups per XCD
  int js = slot >> 4;                // 0..7
  int tid = threadIdx.x;
  int w = tid >> 6;
  int lane = tid & 63;
  int i0 = rg * 64;
  int jbase = js * 1024 + w * 256;
  int c = lane & 15;   // operand row/col selector, D column (i)
  int q = lane >> 4;   // k-quad; D row group (j)

  // B-operand fragments (i-side), persistent: B[k][col=c] = X[i0+it*16+c][k]
  bf16x8 xi[4][2];
#pragma unroll
  for (int it = 0; it < 4; ++it)
#pragma unroll
    for (int kb = 0; kb < 2; ++kb)
      xi[it][kb] = *reinterpret_cast<const bf16x8*>(
          xb + (size_t)(i0 + it * 16 + c) * DIM + kb * 32 + q * 8);

  // Per-it A row pointer: row i0+it*16+c, col jbase + q*4 (+ jt*16 folds to imm)
  const float* pA[4];
#pragma unroll
  for (int it = 0; it < 4; ++it)
    pA[it] = A + (size_t)(i0 + it * 16 + c) * N + jbase + q * 4;

  float sacc[4] = {0.f, 0.f, 0.f, 0.f};

  f32x4 a_buf[2][4];
  bf16x8 xj_buf[2][2];

  // prologue: jt=0 loads
#pragma unroll
  for (int it = 0; it < 4; ++it)
    a_buf[0][it] = *reinterpret_cast<const f32x4*>(pA[it]);
  {
    const unsigned short* pj = xb + (size_t)(jbase + c) * DIM + q * 8;
    xj_buf[0][0] = *reinterpret_cast<const bf16x8*>(pj);
    xj_buf[0][1] = *reinterpret_cast<const bf16x8*>(pj + 32);
  }

#pragma unroll
  for (int jt = 0; jt < 16; ++jt) {
    const int cur = jt & 1, nxt = cur ^ 1;
    if (jt < 15) {
#pragma unroll
      for (int it = 0; it < 4; ++it)
        a_buf[nxt][it] =
            *reinterpret_cast<const f32x4*>(pA[it] + (jt + 1) * 16);
      const unsigned short* pj =
          xb + (size_t)(jbase + (jt + 1) * 16 + c) * DIM + q * 8;
      xj_buf[nxt][0] = *reinterpret_cast<const bf16x8*>(pj);
      xj_buf[nxt][1] = *reinterpret_cast<const bf16x8*>(pj + 32);
    }
#pragma unroll
    for (int it = 0; it < 4; ++it) {
      f32x4 g = {0.f, 0.f, 0.f, 0.f};
      g = __builtin_amdgcn_mfma_f32_16x16x32_bf16(xj_buf[cur][0], xi[it][0], g, 0, 0, 0);
      g = __builtin_amdgcn_mfma_f32_16x16x32_bf16(xj_buf[cur][1], xi[it][1], g, 0, 0, 0);
      f32x4 a4 = a_buf[cur][it];
      sacc[it] = fmaf(a4[0], g[0], sacc[it]);
      sacc[it] = fmaf(a4[1], g[1], sacc[it]);
      sacc[it] = fmaf(a4[2], g[2], sacc[it]);
      sacc[it] = fmaf(a4[3], g[3], sacc[it]);
    }
  }

  // Sum over q (j sub-blocks within the wave): lanes c, c+16, c+32, c+48
#pragma unroll
  for (int it = 0; it < 4; ++it) {
    float s = sacc[it];
    s += __shfl_xor(s, 16);
    s += __shfl_xor(s, 32);
    sacc[it] = s;
  }

  __shared__ float red[4][64];
  if (q == 0) {
#pragma unroll
    for (int it = 0; it < 4; ++it)
      red[w][it * 16 + c] = sacc[it];
  }
  __syncthreads();
  if (tid < 64) {
    float s = red[0][tid] + red[1][tid] + red[2][tid] + red[3][tid];
    spart[(size_t)js * N + i0 + tid] = s;
  }
}

// out[i][d] = 1 - 0.1*x[i][d] - 0.01*sum_c spart[c][i]; 131072 threads, 4 elems each
__global__ void finish_kernel(const float* __restrict__ x,
                              const float* __restrict__ spart,
                              float* __restrict__ out) {
  int gid = blockIdx.x * blockDim.x + threadIdx.x;
  float4 xv = reinterpret_cast<const float4*>(x)[gid];
  int i = gid >> 4;  // (gid*4)/64
  float s = 0.f;
#pragma unroll
  for (int cc = 0; cc < 8; ++cc) s += spart[(size_t)cc * N + i];
  float4 o;
  o.x = 1.0f - 0.1f * xv.x - 0.01f * s;
  o.y = 1.0f - 0.1f * xv.y - 0.01f * s;
  o.z = 1.0f - 0.1f * xv.z - 0.01f * s;
  o.w = 1.0f - 0.1f * xv.w - 0.01f * s;
  reinterpret_cast<float4*>(out)[gid] = o;
}

extern "C" void kernel_launch(void* const* d_in, const int* in_sizes, int n_in,
                              void* d_out, int out_size, void* d_ws, size_t ws_size,
                              hipStream_t stream) {
  // d_in[0] = t (unused), d_in[1] = x f32 [8192][64], d_in[2] = A f32 [8192][8192]
  const float* x = (const float*)d_in[1];
  const float* A = (const float*)d_in[2];
  float* out = (float*)d_out;

  unsigned short* xb = (unsigned short*)d_ws;                  // 1 MB bf16 x
  float* spart = (float*)((char*)d_ws + (size_t)N * DIM * 2);  // 256 KB partials

  cvt_kernel<<<512, 256, 0, stream>>>(x, xb);
  main_kernel<<<1024, 256, 0, stream>>>(A, xb, spart);
  finish_kernel<<<512, 256, 0, stream>>>(x, spart, out);
}